// Round 7
// baseline (232.214 us; speedup 1.0000x reference)
//
#include <hip/hip_runtime.h>
#include <math.h>

typedef unsigned short u16;
typedef __attribute__((ext_vector_type(8))) short short8;   // 8 bf16 = 4 VGPRs
typedef __attribute__((ext_vector_type(4))) short short4v;  // 4 bf16 = 2 VGPRs
typedef __attribute__((ext_vector_type(4))) float f32x4;    // MFMA C/D frag
typedef __attribute__((ext_vector_type(2))) unsigned int uint2v;
typedef __attribute__((ext_vector_type(4))) unsigned int uint4v;

constexpr int Bn = 4, Sn = 2048, Dn = 1024, Hn = 16;
constexpr float SCL = 0.125f * 1.44269504f;  // 1/sqrt(64) * log2(e), folded into Wq

__device__ __forceinline__ u16 f2bf(float f) {  // RNE float->bf16
  unsigned u = __float_as_uint(f);
  u += 0x7fffu + ((u >> 16) & 1u);
  return (u16)(u >> 16);
}

__device__ __forceinline__ f32x4 mfma32(short8 a, short8 b, f32x4 c) {
  return __builtin_amdgcn_mfma_f32_16x16x32_bf16(a, b, c, 0, 0, 0);
}

__device__ __forceinline__ void gl_lds16(const u16* g, u16* l) {
  __builtin_amdgcn_global_load_lds(
      (const __attribute__((address_space(1))) unsigned int*)g,
      (__attribute__((address_space(3))) unsigned int*)l, 16, 0, 0);
}

// Barrier brackets for the 8-phase schedule. sched_barrier(0) on BOTH sides
// of every s_barrier: s_barrier is IntrNoMem to LLVM, so plain LDS loads CAN
// be moved across it (rule #18 family) -- the sched fences pin program order.
#define BAR_IN()                                          \
  do {                                                    \
    __builtin_amdgcn_sched_barrier(0);                    \
    __builtin_amdgcn_s_barrier();                         \
    asm volatile("s_waitcnt lgkmcnt(0)" ::: "memory");    \
    __builtin_amdgcn_sched_barrier(0);                    \
    __builtin_amdgcn_s_setprio(1);                        \
  } while (0)
#define BAR_OUT()                                         \
  do {                                                    \
    __builtin_amdgcn_s_setprio(0);                        \
    __builtin_amdgcn_sched_barrier(0);                    \
    __builtin_amdgcn_s_barrier();                         \
    __builtin_amdgcn_sched_barrier(0);                    \
  } while (0)
#define BAR_OUT_VM(N)                                     \
  do {                                                    \
    __builtin_amdgcn_s_setprio(0);                        \
    __builtin_amdgcn_sched_barrier(0);                    \
    asm volatile("s_waitcnt vmcnt(" #N ")" ::: "memory"); \
    __builtin_amdgcn_s_barrier();                         \
    __builtin_amdgcn_sched_barrier(0);                    \
  } while (0)

// ---------------------------------------------------------------------------
// One launch for all f32->bf16 casts. Blocks 0..8191: x. Then 1024 each for
// wq (pre-scaled by SCL), wk, wv, wo.
// ---------------------------------------------------------------------------
__global__ __launch_bounds__(256) void cast_all(
    const float4* __restrict__ x, const float4* __restrict__ wq,
    const float4* __restrict__ wk, const float4* __restrict__ wv,
    const float4* __restrict__ wo, ushort4* __restrict__ xb,
    ushort4* __restrict__ wqb, ushort4* __restrict__ wkb,
    ushort4* __restrict__ wvb, ushort4* __restrict__ wob) {
  const int blk = blockIdx.x;
  const float4* in;
  ushort4* out;
  int base;
  float s = 1.0f;
  if (blk < 8192) {
    in = x; out = xb; base = blk;
  } else if (blk < 9216) {
    in = wq; out = wqb; base = blk - 8192; s = SCL;
  } else if (blk < 10240) {
    in = wk; out = wkb; base = blk - 9216;
  } else if (blk < 11264) {
    in = wv; out = wvb; base = blk - 10240;
  } else {
    in = wo; out = wob; base = blk - 11264;
  }
  const int i = base * 256 + threadIdx.x;
  const float4 f = in[i];
  ushort4 o;
  o.x = f2bf(f.x * s); o.y = f2bf(f.y * s);
  o.z = f2bf(f.z * s); o.w = f2bf(f.w * s);
  out[i] = o;
}

// ---------------------------------------------------------------------------
// QKV GEMM, 256x256 tile, BK=64, 8 waves (512 thr), 8-PHASE schedule with
// counted vmcnt (T2+T3+T4+T5, m201 template). The previous 128-square
// 2-barrier loop measured 850 TF / 35.7% MfmaUtil == the m97 structural
// ceiling (vmcnt(0) drain each K-step); this schedule keeps 3 staged
// half-tiles in flight ACROSS barriers (vmcnt(6) only at phases 4/8).
//
// LDS (128 KB, u16[65536]): A bufs at 0/16384, B bufs at 32768/49152.
// Row permutation so each 16KB stage half is lane-linear for gl_lds:
//   A: lds_row = global row with bits 6,7 swapped  (half = mi>>2)
//   B: lds_row = ((n>>5&1)<<7)|((n>>6)<<5)|(n&31)  (half = ni>>1)
// + chunk swizzle cl ^ (lds_row&7) (verified conflict-free, 0 in counters).
//
// Per iteration i: phases 1-4 compute K-tile 2i (buf0) quadrants
// q(Agrp,Bgrp) = (0,0)(0,1)(1,1)(1,0); phases 5-8 same for 2i+1 (buf1).
// Stage stream (1 half/phase): ph1:(2i+1).B1  ph2:(2i+2).Alo  ph3:(2i+2).B0
// ph4:(2i+2).Ahi  ph5:(2i+2).B1  ph6:(2i+3).Alo  ph7:(2i+3).B0
// ph8:(2i+3).Ahi. Every dest region is free (read fully in an earlier
// phase, post-barrier) and every read is covered by vmcnt(6)@ph4/8
// (retires the 4th-newest half = the B1 completing the next buffer).
// Prologue: 7 halves (kt0 x4, kt1 Alo/B0/Ahi) + vmcnt(6). Tail iter (i=7):
// ph1 stages (15).B1, then no stages; vmcnt(0) at ph4.
// ---------------------------------------------------------------------------
__global__ __launch_bounds__(512, 2) void gemm_qkv8(
    const u16* __restrict__ A, const u16* __restrict__ Wq,
    const u16* __restrict__ Wk, const u16* __restrict__ Wv,
    u16* __restrict__ Cq, u16* __restrict__ Ck, u16* __restrict__ Vt) {
  __shared__ u16 lds[65536];

  const int t = threadIdx.x;
  const int w8 = t >> 6, l = t & 63;
  const int wr = w8 >> 2, wc = w8 & 3;      // wave grid 2M x 4N
  const int q = l >> 4, r = l & 15;
  const int m0 = blockIdx.x * 256, n0 = blockIdx.y * 256;
  const int z = blockIdx.z;
  const u16* __restrict__ W = z == 0 ? Wq : z == 1 ? Wk : Wv;

  // Per-thread stage sources (ha=0 base; ha=1 adds a constant row offset:
  // A: +64 rows = 65536 elems; B: +32 rows = 32768 elems).
  const u16* asrc[2];
  const u16* wsrc[2];
#pragma unroll
  for (int ii = 0; ii < 2; ++ii) {
    const int c = t + ii * 512, lr = c >> 3, cl = c & 7;
    const int cg = cl ^ (lr & 7);
    const int rowA0 = ((lr >> 6) << 7) + (lr & 63);
    const int rowB0 = ((lr >> 5) << 6) + (lr & 31);
    asrc[ii] = A + (size_t)(m0 + rowA0) * 1024 + cg * 8;
    wsrc[ii] = W + (size_t)(n0 + rowB0) * 1024 + cg * 8;
  }
  const int dl0 = t * 8;  // lds dest (u16) for ii=0; ii=1 adds 4096

  auto STA = [&](int kt, int ha) {
#pragma unroll
    for (int ii = 0; ii < 2; ++ii)
      gl_lds16(asrc[ii] + ha * 65536 + kt * 64,
               &lds[(kt & 1) * 16384 + ha * 8192 + dl0 + ii * 4096]);
  };
  auto STB = [&](int kt, int ha) {
#pragma unroll
    for (int ii = 0; ii < 2; ++ii)
      gl_lds16(wsrc[ii] + ha * 32768 + kt * 64,
               &lds[32768 + (kt & 1) * 16384 + ha * 8192 + dl0 + ii * 4096]);
  };

  f32x4 acc[8][4] = {};
  short8 Af[4][2];      // current A frag group (4 mi x 2 kf)
  short8 Bf[2][2][2];   // both B groups (grp x n2 x kf)

  auto LDA = [&](int bufbase, int grp) {
#pragma unroll
    for (int m2 = 0; m2 < 4; ++m2) {
      const int lro = bufbase + grp * 8192 + (wr * 64 + m2 * 16 + r) * 64;
#pragma unroll
      for (int kf = 0; kf < 2; ++kf)
        Af[m2][kf] = *(const short8*)&lds[lro + (((kf * 4 + q) ^ (r & 7)) * 8)];
    }
  };
  auto LDB = [&](int bufbase, int grp) {
#pragma unroll
    for (int n2 = 0; n2 < 2; ++n2) {
      const int lro = bufbase + grp * 8192 + (wc * 32 + n2 * 16 + r) * 64;
#pragma unroll
      for (int kf = 0; kf < 2; ++kf)
        Bf[grp][n2][kf] =
            *(const short8*)&lds[lro + (((kf * 4 + q) ^ (r & 7)) * 8)];
    }
  };
  auto MM = [&](int ag, int bg) {
#pragma unroll
    for (int kf = 0; kf < 2; ++kf)  // kf outer: 8-deep independent chains
#pragma unroll
      for (int m2 = 0; m2 < 4; ++m2)
#pragma unroll
        for (int n2 = 0; n2 < 2; ++n2)
          acc[ag * 4 + m2][bg * 2 + n2] =
              mfma32(Af[m2][kf], Bf[bg][n2][kf], acc[ag * 4 + m2][bg * 2 + n2]);
  };

  // prologue: kt0 complete + kt1 {Alo,B0,Ahi}; keep 3 halves in flight
  STA(0, 0); STB(0, 0); STA(0, 1); STB(0, 1);
  STA(1, 0); STB(1, 0); STA(1, 1);
  asm volatile("s_waitcnt vmcnt(6)" ::: "memory");
  __builtin_amdgcn_s_barrier();
  __builtin_amdgcn_sched_barrier(0);

#pragma unroll 1
  for (int i = 0; i < 8; ++i) {
    const int kc = 2 * i;
    const bool full = (i < 7);
    // ph1: kt kc (buf0), quadrant (A0,B0)
    LDA(0, 0); LDB(32768, 0);
    STB(kc + 1, 1);
    BAR_IN(); MM(0, 0); BAR_OUT();
    // ph2: (A0,B1)
    LDB(32768, 1);
    if (full) STA(kc + 2, 0);
    BAR_IN(); MM(0, 1); BAR_OUT();
    // ph3: (A1,B1)
    LDA(0, 1);
    if (full) STB(kc + 2, 0);
    BAR_IN(); MM(1, 1); BAR_OUT();
    // ph4: (A1,B0); vmcnt completes buf1 (kt kc+1)
    if (full) STA(kc + 2, 1);
    BAR_IN(); MM(1, 0);
    if (full) { BAR_OUT_VM(6); } else { BAR_OUT_VM(0); }
    // ph5: kt kc+1 (buf1), (A0,B0)
    LDA(16384, 0); LDB(49152, 0);
    if (full) STB(kc + 2, 1);
    BAR_IN(); MM(0, 0); BAR_OUT();
    // ph6: (A0,B1)
    LDB(49152, 1);
    if (full) STA(kc + 3, 0);
    BAR_IN(); MM(0, 1); BAR_OUT();
    // ph7: (A1,B1)
    LDA(16384, 1);
    if (full) STB(kc + 3, 0);
    BAR_IN(); MM(1, 1); BAR_OUT();
    // ph8: (A1,B0); vmcnt completes buf0 (kt kc+2)
    if (full) {
      STA(kc + 3, 1);
      BAR_IN(); MM(1, 0); BAR_OUT_VM(6);
    } else {
      BAR_IN(); MM(1, 0); BAR_OUT();
    }
  }

  // epilogue
  if (z == 2) {
    // V^T tiles (b,h,jt): V^T[hd][key], chunk c2=q+4*((mi&3)>>1) at slot
    // c2^(hd&7), half (mi&3)&1 -- identical vt2 format to the 128-sq kernel.
    const int bq = m0 >> 11;
    const int hh = (n0 >> 6) + wc;
#pragma unroll
    for (int mi = 0; mi < 8; ++mi) {
      const int jt = ((m0 & 2047) >> 6) + wr * 2 + (mi >> 2);
      const int m3 = mi & 3;
      u16* vt_t = Vt + ((size_t)((bq * 16 + hh) * 32) + jt) * 4096;
      const int slot = (((q + 4 * (m3 >> 1)) ^ (r & 7)) * 8) + (m3 & 1) * 4;
#pragma unroll
      for (int ni = 0; ni < 4; ++ni) {
        short4v pk;
#pragma unroll
        for (int e = 0; e < 4; ++e) pk[e] = (short)f2bf(acc[mi][ni][e]);
        *(short4v*)&vt_t[(ni * 16 + r) * 64 + slot] = pk;
      }
    }
  } else {
    u16* __restrict__ Cb = z ? Ck : Cq;
#pragma unroll
    for (int mi = 0; mi < 8; ++mi) {
      const int row = m0 + wr * 128 + mi * 16 + q * 4;
#pragma unroll
      for (int ni = 0; ni < 4; ++ni) {
        const int col = n0 + wc * 64 + ni * 16 + r;
#pragma unroll
        for (int e = 0; e < 4; ++e)
          Cb[(size_t)(row + e) * 1024 + col] = f2bf(acc[mi][ni][e]);
      }
    }
  }
}

// ---------------------------------------------------------------------------
// Output GEMM (f32 out): unchanged 128x128 two-barrier BK=64 structure.
// ---------------------------------------------------------------------------
__global__ __launch_bounds__(256) void gemm_out(const u16* __restrict__ A,
                                                const u16* __restrict__ W,
                                                float* __restrict__ C) {
  __shared__ u16 Asm[128 * 64];
  __shared__ u16 Wsm[128 * 64];
  const int t = threadIdx.x;
  const int w = t >> 6, l = t & 63;
  const int wy = w >> 1, wx = w & 1;
  const int q = l >> 4, r = l & 15;
  const int m0 = blockIdx.x * 128, n0 = blockIdx.y * 128;

  f32x4 acc[4][4] = {};

  for (int k0 = 0; k0 < 1024; k0 += 64) {
    __syncthreads();
#pragma unroll
    for (int i = 0; i < 4; ++i) {
      const int c = t + i * 256;
      const int row = c >> 3, cl = c & 7;
      const int cg = cl ^ (row & 7);
      gl_lds16(A + (size_t)(m0 + row) * 1024 + k0 + cg * 8, &Asm[c * 8]);
      gl_lds16(W + (size_t)(n0 + row) * 1024 + k0 + cg * 8, &Wsm[c * 8]);
    }
    __syncthreads();
#pragma unroll
    for (int kf = 0; kf < 2; ++kf) {
      short8 af[4], bf[4];
#pragma unroll
      for (int mi = 0; mi < 4; ++mi) {
        const int rowA = wy * 64 + mi * 16 + r;
        af[mi] = *(const short8*)&Asm[rowA * 64 + ((kf * 4 + q) ^ (rowA & 7)) * 8];
        const int rowB = wx * 64 + mi * 16 + r;
        bf[mi] = *(const short8*)&Wsm[rowB * 64 + ((kf * 4 + q) ^ (rowB & 7)) * 8];
      }
#pragma unroll
      for (int mi = 0; mi < 4; ++mi)
#pragma unroll
        for (int ni = 0; ni < 4; ++ni)
          acc[mi][ni] = mfma32(af[mi], bf[ni], acc[mi][ni]);
    }
  }

#pragma unroll
  for (int mi = 0; mi < 4; ++mi) {
    const int row = m0 + wy * 64 + mi * 16 + q * 4;
#pragma unroll
    for (int ni = 0; ni < 4; ++ni) {
      const int col = n0 + wx * 64 + ni * 16 + r;
#pragma unroll
      for (int e = 0; e < 4; ++e)
        C[(size_t)(row + e) * 1024 + col] = acc[mi][ni][e];
    }
  }
}

// ---------------------------------------------------------------------------
// Flash attention v10 (unchanged from R6; attn dropped out of top-5):
// LPT grid, XCD pinning, K double-buffer + single V buffer (24 KB), counted
// vmcnt(4) before PV, register softmax via S^T trick, PV via mfma32.
// ---------------------------------------------------------------------------
__global__ __launch_bounds__(128) void attn_v10(const u16* __restrict__ Qb,
                                                const u16* __restrict__ Kb,
                                                const u16* __restrict__ Vt,
                                                u16* __restrict__ Ob) {
  const int i = blockIdx.x;                      // 0..2047
  const int st = 31 - (i >> 6);                  // heavy q-tiles first (LPT)
  const int grp = (i & 7) + 8 * ((i >> 3) & 7);  // (b,h) group, XCD-pinned
  const int b = grp >> 4, h = grp & 15;
  const int t = threadIdx.x;
  const int w = t >> 6, l = t & 63;
  const int q = l >> 4, r = l & 15;

  __shared__ u16 Kd[2][4096];   // K double buffer (16 KB)
  __shared__ u16 Vd[4096];      // V single buffer (8 KB)

  const size_t kgbase = (size_t)(b * Sn) * Dn + h * 64;
  const size_t vgbase = (size_t)((b * Hn + h) * 32) * 4096;

  const u16* kg[4];
  const u16* vg[4];
#pragma unroll
  for (int ii = 0; ii < 4; ++ii) {
    const int c = t + ii * 128, row = c >> 3, cl = c & 7;
    kg[ii] = Kb + kgbase + (size_t)row * Dn + (cl ^ (row & 7)) * 8;
    vg[ii] = Vt + vgbase + c * 8;
  }
  const int rx = r & 7;
  const int b0 = r * 64 + ((q ^ rx) * 8);
  const int b1 = r * 64 + (((4 + q) ^ rx) * 8);

  const int qb64 = st * 64;

  short8 Qf[2][2];
#pragma unroll
  for (int mi = 0; mi < 2; ++mi)
#pragma unroll
    for (int kf = 0; kf < 2; ++kf)
      Qf[mi][kf] = *(const short8*)(Qb +
          (size_t)(b * Sn + qb64 + w * 32 + mi * 16 + r) * Dn + h * 64 +
          kf * 32 + q * 8);

  f32x4 O[2][4] = {};
  float l_[2] = {0.f, 0.f};

#pragma unroll
  for (int ii = 0; ii < 4; ++ii)
    gl_lds16(kg[ii], &Kd[0][(t + ii * 128) * 8]);

  const u16* kgt[4];
  const u16* vgt[4];
#pragma unroll
  for (int ii = 0; ii < 4; ++ii) {
    kgt[ii] = kg[ii] + 64 * Dn;
    vgt[ii] = vg[ii];
  }

  for (int jt = 0; jt <= st; ++jt) {
    __syncthreads();  // vmcnt(0)+barrier: K(jt) staged; V(jt-1) reads done

#pragma unroll
    for (int ii = 0; ii < 4; ++ii) {
      gl_lds16(vgt[ii], &Vd[(t + ii * 128) * 8]);
      vgt[ii] += 4096;
    }
    if (jt < st) {
      u16* kl = &Kd[(jt + 1) & 1][0];
#pragma unroll
      for (int ii = 0; ii < 4; ++ii) {
        gl_lds16(kgt[ii], kl + (t + ii * 128) * 8);
        kgt[ii] += 64 * Dn;
      }
    }

    const u16* KtA = &Kd[jt & 1][b0];
    const u16* KtB = &Kd[jt & 1][b1];

    short8 Kf[4][2];
#pragma unroll
    for (int ni = 0; ni < 4; ++ni) {
      Kf[ni][0] = *(const short8*)(KtA + ni * 1024);
      Kf[ni][1] = *(const short8*)(KtB + ni * 1024);
    }

    f32x4 S[2][4] = {};
    __builtin_amdgcn_s_setprio(1);
#pragma unroll
    for (int ni = 0; ni < 4; ++ni)
#pragma unroll
      for (int kf = 0; kf < 2; ++kf) {
        S[0][ni] = mfma32(Kf[ni][kf], Qf[0][kf], S[0][ni]);
        S[1][ni] = mfma32(Kf[ni][kf], Qf[1][kf], S[1][ni]);
      }
    __builtin_amdgcn_s_setprio(0);

    if (jt == st) {
#pragma unroll
      for (int mi = 0; mi < 2; ++mi) {
        const int qrow = w * 32 + mi * 16 + r;
#pragma unroll
        for (int ni = 0; ni < 4; ++ni) {
          const int key = ni * 16 + q * 4;
#pragma unroll
          for (int e = 0; e < 4; ++e)
            if (key + e > qrow) S[mi][ni][e] = -3.0e38f;
        }
      }
    }

    short8 P8[2][2];
#pragma unroll
    for (int mi = 0; mi < 2; ++mi)
#pragma unroll
      for (int np = 0; np < 2; ++np) {
        unsigned pw[4];
#pragma unroll
        for (int half = 0; half < 2; ++half) {
          const int ni = 2 * np + half;
          const float p0 = __builtin_amdgcn_exp2f(S[mi][ni][0]);
          const float p1 = __builtin_amdgcn_exp2f(S[mi][ni][1]);
          const float p2 = __builtin_amdgcn_exp2f(S[mi][ni][2]);
          const float p3 = __builtin_amdgcn_exp2f(S[mi][ni][3]);
          l_[mi] += (p0 + p1) + (p2 + p3);
          unsigned plo, phi;
          asm("v_cvt_pk_bf16_f32 %0, %1, %2" : "=v"(plo) : "v"(p0), "v"(p1));
          asm("v_cvt_pk_bf16_f32 %0, %1, %2" : "=v"(phi) : "v"(p2), "v"(p3));
          pw[half * 2] = plo;
          pw[half * 2 + 1] = phi;
        }
        const uint4v pk4 = {pw[0], pw[1], pw[2], pw[3]};
        P8[mi][np] = __builtin_bit_cast(short8, pk4);
      }

    if (jt < st)
      asm volatile("s_waitcnt vmcnt(4)" ::: "memory");
    else
      asm volatile("s_waitcnt vmcnt(0)" ::: "memory");
    __builtin_amdgcn_s_barrier();
    __builtin_amdgcn_sched_barrier(0);

    __builtin_amdgcn_s_setprio(1);
#pragma unroll
    for (int np = 0; np < 2; ++np) {
      const int vb = np ? b1 : b0;
#pragma unroll
      for (int ni2 = 0; ni2 < 4; ++ni2) {
        const short8 vvx = *(const short8*)(&Vd[vb + ni2 * 1024]);
        O[0][ni2] = mfma32(vvx, P8[0][np], O[0][ni2]);
        O[1][ni2] = mfma32(vvx, P8[1][np], O[1][ni2]);
      }
    }
    __builtin_amdgcn_s_setprio(0);
  }

#pragma unroll
  for (int mi = 0; mi < 2; ++mi) {
    float s = l_[mi];
    s += __shfl_xor(s, 16, 64);
    s += __shfl_xor(s, 32, 64);
    const float rl = __builtin_amdgcn_rcpf(s);
#pragma unroll
    for (int ni2 = 0; ni2 < 4; ++ni2) {
      short4v o;
#pragma unroll
      for (int e = 0; e < 4; ++e) o[e] = (short)f2bf(O[mi][ni2][e] * rl);
      *(short4v*)(Ob + (size_t)(b * Sn + qb64 + w * 32 + mi * 16 + r) * Dn +
                  h * 64 + ni2 * 16 + q * 4) = o;
    }
  }
}

// ---------------------------------------------------------------------------
extern "C" void kernel_launch(void* const* d_in, const int* in_sizes, int n_in,
                              void* d_out, int out_size, void* d_ws, size_t ws_size,
                              hipStream_t stream) {
  const float* x  = (const float*)d_in[0];
  const float* wq = (const float*)d_in[1];
  const float* wk = (const float*)d_in[2];
  const float* wv = (const float*)d_in[3];
  const float* wo = (const float*)d_in[4];
  float* out = (float*)d_out;

  u16* xb  = (u16*)d_ws;            // 8M u16
  u16* wqb = xb + 8388608;
  u16* wkb = wqb + 1048576;
  u16* wvb = wkb + 1048576;
  u16* wob = wvb + 1048576;
  u16* qb  = wob + 1048576;         // 8M each
  u16* kb  = qb + 8388608;
  u16* vt2 = kb + 8388608;          // V^T tiles, pre-swizzled
  u16* aob = vt2 + 8388608;

  cast_all<<<12288, 256, 0, stream>>>(
      (const float4*)x, (const float4*)wq, (const float4*)wk,
      (const float4*)wv, (const float4*)wo, (ushort4*)xb, (ushort4*)wqb,
      (ushort4*)wkb, (ushort4*)wvb, (ushort4*)wob);

  gemm_qkv8<<<dim3(32, 4, 3), 512, 0, stream>>>(xb, wqb, wkb, wvb, qb, kb, vt2);

  attn_v10<<<2048, 128, 0, stream>>>(qb, kb, vt2, aob);

  gemm_out<<<dim3(64, 8), 256, 0, stream>>>(aob, wob, out);
}